// Round 1
// baseline (346.648 us; speedup 1.0000x reference)
//
#include <hip/hip_runtime.h>
#include <math.h>

// GAT layer: B=16,S=64 -> 1024 independent graphs of N=256 nodes, F=O=64, H=1.
// One block (256 threads) per graph.

constexpr int NN = 256;   // nodes
constexpr int FF = 64;    // in features
constexpr int OO = 64;    // out features
constexpr int HP = OO + 4; // padded LDS row: 68 floats = 272B, 16B-aligned rows

__global__ __launch_bounds__(256) void gat_fused(
    const float* __restrict__ x,        // [BS, N, F]
    const int*   __restrict__ adj,      // [BS, N, N]  (adj[j][i]!=0 => edge j->i)
    const float* __restrict__ W,        // [F, O]
    const float* __restrict__ att_src,  // [O]
    const float* __restrict__ att_dst,  // [O]
    const float* __restrict__ bias,     // [O]
    float* __restrict__ out)            // [BS, N, O]
{
    __shared__ __align__(16) float h_s[NN][HP];          // 69,632 B
    __shared__ float as_s[NN];                           //  1,024 B
    __shared__ unsigned long long mask_s[NN * 4];        //  8,192 B

    const int tid  = threadIdx.x;       // target node i
    const int bs   = blockIdx.x;
    const int lane = tid & 63;
    const int wave = tid >> 6;

    const float* xg   = x + (size_t)bs * NN * FF;
    const int4*  adjv = reinterpret_cast<const int4*>(adj + (size_t)bs * NN * NN);
    float*       outg = out + (size_t)bs * NN * OO;

    // ---- Stage adjacency as a bitmap: row j, entry i -> bit ----
    // adjv[j*64 + lane] = adj[j][4*lane .. 4*lane+3]; coalesced 16B/lane.
    // mask_s[j*4+q] bit ln == (adj[j][4*ln+q] != 0)
    #pragma unroll 4
    for (int r = 0; r < 64; ++r) {
        int j = r * 4 + wave;
        int4 v = adjv[j * 64 + lane];
        unsigned long long b0 = __ballot(v.x != 0);
        unsigned long long b1 = __ballot(v.y != 0);
        unsigned long long b2 = __ballot(v.z != 0);
        unsigned long long b3 = __ballot(v.w != 0);
        if (lane < 4) {
            unsigned long long bv = (lane == 0) ? b0 : (lane == 1) ? b1
                                  : (lane == 2) ? b2 : b3;
            mask_s[j * 4 + lane] = bv;
        }
    }

    // ---- h row i = x_row_i @ W ; a_s[i], a_d[i] ----
    float acc[OO];
    #pragma unroll
    for (int o = 0; o < OO; ++o) acc[o] = 0.f;

    const float4* xv = reinterpret_cast<const float4*>(xg + tid * FF);
    const float4* Wv = reinterpret_cast<const float4*>(W);
    for (int k4 = 0; k4 < FF / 4; ++k4) {
        float4 xq = xv[k4];
        float xs[4] = {xq.x, xq.y, xq.z, xq.w};
        #pragma unroll
        for (int kk = 0; kk < 4; ++kk) {
            float xk = xs[kk];
            const float4* wrow = Wv + (k4 * 4 + kk) * (OO / 4);
            #pragma unroll
            for (int o4 = 0; o4 < OO / 4; ++o4) {
                float4 w = wrow[o4];   // wave-uniform -> scalar/broadcast load
                acc[o4 * 4 + 0] = fmaf(xk, w.x, acc[o4 * 4 + 0]);
                acc[o4 * 4 + 1] = fmaf(xk, w.y, acc[o4 * 4 + 1]);
                acc[o4 * 4 + 2] = fmaf(xk, w.z, acc[o4 * 4 + 2]);
                acc[o4 * 4 + 3] = fmaf(xk, w.w, acc[o4 * 4 + 3]);
            }
        }
    }

    float as_i = 0.f, ad_i = 0.f;
    {
        const float4* sv = reinterpret_cast<const float4*>(att_src);
        const float4* dv = reinterpret_cast<const float4*>(att_dst);
        #pragma unroll
        for (int o4 = 0; o4 < OO / 4; ++o4) {
            float4 a = sv[o4], d = dv[o4];
            as_i += acc[o4*4+0]*a.x + acc[o4*4+1]*a.y + acc[o4*4+2]*a.z + acc[o4*4+3]*a.w;
            ad_i += acc[o4*4+0]*d.x + acc[o4*4+1]*d.y + acc[o4*4+2]*d.z + acc[o4*4+3]*d.w;
        }
    }
    as_s[tid] = as_i;
    #pragma unroll
    for (int o4 = 0; o4 < OO / 4; ++o4) {
        *reinterpret_cast<float4*>(&h_s[tid][o4 * 4]) =
            make_float4(acc[o4*4+0], acc[o4*4+1], acc[o4*4+2], acc[o4*4+3]);
    }
    __syncthreads();

    // ---- Pass 1: row max over valid sources j; cache validity in registers ----
    unsigned int mbits[8];
    #pragma unroll
    for (int q = 0; q < 8; ++q) mbits[q] = 0;
    float m = -3.0e38f;
    const int wsel = tid & 3;
    const int bsh  = tid >> 2;
    #pragma unroll 4
    for (int j = 0; j < NN; ++j) {
        bool nb = (mask_s[j * 4 + wsel] >> bsh) & 1ull;
        bool valid = nb || (j == tid);   // self-loop always present
        if (valid) {
            mbits[j >> 5] |= (1u << (j & 31));
            float e = ad_i + as_s[j];
            e = fmaxf(e, 0.2f * e);      // leaky_relu(e, 0.2)
            m = fmaxf(m, e);
        }
    }

    // ---- Pass 2: unnormalized out accumulation + denominator ----
    float l = 0.f;
    #pragma unroll
    for (int o = 0; o < OO; ++o) acc[o] = 0.f;
    #pragma unroll 2
    for (int j = 0; j < NN; ++j) {
        float e = ad_i + as_s[j];
        e = fmaxf(e, 0.2f * e);
        bool valid = (mbits[j >> 5] >> (j & 31)) & 1u;
        float p = valid ? __expf(e - m) : 0.f;
        l += p;
        const float4* hj = reinterpret_cast<const float4*>(&h_s[j][0]); // broadcast
        #pragma unroll
        for (int o4 = 0; o4 < OO / 4; ++o4) {
            float4 hv = hj[o4];
            acc[o4*4+0] = fmaf(p, hv.x, acc[o4*4+0]);
            acc[o4*4+1] = fmaf(p, hv.y, acc[o4*4+1]);
            acc[o4*4+2] = fmaf(p, hv.z, acc[o4*4+2]);
            acc[o4*4+3] = fmaf(p, hv.w, acc[o4*4+3]);
        }
    }
    float inv = 1.0f / l;   // diagonal always valid -> l > 0

    // ---- Finalize through LDS for coalesced stores ----
    __syncthreads();   // all pass-2 reads of h_s done
    {
        const float4* bv = reinterpret_cast<const float4*>(bias);
        #pragma unroll
        for (int o4 = 0; o4 < OO / 4; ++o4) {
            float4 b = bv[o4];
            *reinterpret_cast<float4*>(&h_s[tid][o4 * 4]) = make_float4(
                fmaf(acc[o4*4+0], inv, b.x),
                fmaf(acc[o4*4+1], inv, b.y),
                fmaf(acc[o4*4+2], inv, b.z),
                fmaf(acc[o4*4+3], inv, b.w));
        }
    }
    __syncthreads();
    float4* outv = reinterpret_cast<float4*>(outg);
    #pragma unroll
    for (int it = 0; it < 16; ++it) {
        int g   = it * 256 + tid;      // float4 index within this graph
        int row = g >> 4;
        int c   = (g & 15) * 4;
        outv[g] = *reinterpret_cast<const float4*>(&h_s[row][c]);
    }
}

extern "C" void kernel_launch(void* const* d_in, const int* in_sizes, int n_in,
                              void* d_out, int out_size, void* d_ws, size_t ws_size,
                              hipStream_t stream) {
    const float* x        = (const float*)d_in[0];
    const int*   adj      = (const int*)  d_in[1];
    const float* W        = (const float*)d_in[2];
    const float* att_src  = (const float*)d_in[3];
    const float* att_dst  = (const float*)d_in[4];
    const float* bias     = (const float*)d_in[5];
    float*       out      = (float*)d_out;

    dim3 grid(1024);   // B*S graphs
    dim3 block(256);   // one thread per node
    hipLaunchKernelGGL(gat_fused, grid, block, 0, stream,
                       x, adj, W, att_src, att_dst, bias, out);
}

// Round 2
// 264.483 us; speedup vs baseline: 1.3107x; 1.3107x over previous
//
#include <hip/hip_runtime.h>
#include <math.h>

// GAT: 1024 independent graphs (B*S), N=256 nodes, F=O=64, H=1.
// One block (256 threads = 4 waves) per graph.
// Phase A: h = x@W in fp32 per-thread; scores a_s/a_d fp32.
// Pass 1: per-target max m and denom l (two-pass softmax, fp32).
// Pass 2: out = alpha @ h via v_mfma_f32_16x16x32_f16, alpha pre-normalized.

constexpr int NN = 256;
constexpr int FF = 64;
constexpr int OO = 64;
constexpr int HT_STRIDE = 280;  // f16 elems; 560 B row stride (odd multiple of 16B -> conflict-free b128)
constexpr int AL_STRIDE = 72;   // f16 elems; 144 B row stride (odd multiple of 16B)

constexpr int SMEM_HT = 64 * HT_STRIDE * 2;          // 35840 B: hT[64][280] f16
constexpr int SMEM_AL = NN * AL_STRIDE * 2;          // 36864 B: alpha[256][72] f16 (overlaid w/ mask)
constexpr int SMEM_AS = NN * 4;                      //  1024 B: a_s[256] f32
constexpr int SMEM_TOTAL = SMEM_HT + SMEM_AL + SMEM_AS; // 73728 B -> 2 blocks/CU

typedef _Float16 half8 __attribute__((ext_vector_type(8)));
typedef float f32x4 __attribute__((ext_vector_type(4)));

__global__ __launch_bounds__(256) void gat_fused(
    const float* __restrict__ x,        // [BS, N, F]
    const int*   __restrict__ adj,      // [BS, N, N]  adj[j][i]!=0 => edge j->i
    const float* __restrict__ W,        // [F, O]
    const float* __restrict__ att_src,  // [O]
    const float* __restrict__ att_dst,  // [O]
    const float* __restrict__ bias,     // [O]
    float* __restrict__ out)            // [BS, N, O]
{
    __shared__ __align__(16) unsigned char smem[SMEM_TOTAL];
    _Float16* hT = (_Float16*)smem;                                   // [64][HT_STRIDE]
    _Float16* al = (_Float16*)(smem + SMEM_HT);                       // [256][AL_STRIDE]
    unsigned long long* mask_s = (unsigned long long*)(smem + SMEM_HT); // overlay on al
    float* as_s = (float*)(smem + SMEM_HT + SMEM_AL);                 // [256]

    const int tid  = threadIdx.x;       // target node i
    const int bs   = blockIdx.x;
    const int lane = tid & 63;
    const int wv   = tid >> 6;

    const float* xg   = x + (size_t)bs * NN * FF;
    const int4*  adjv = reinterpret_cast<const int4*>(adj + (size_t)bs * NN * NN);
    float*       outg = out + (size_t)bs * NN * OO;

    // ---- Stage adjacency as bitmap: mask_s[j*4+q] bit ln == (adj[j][4*ln+q]!=0) ----
    #pragma unroll 4
    for (int r = 0; r < 64; ++r) {
        int j = r * 4 + wv;
        int4 v = adjv[j * 64 + lane];
        unsigned long long b0 = __ballot(v.x != 0);
        unsigned long long b1 = __ballot(v.y != 0);
        unsigned long long b2 = __ballot(v.z != 0);
        unsigned long long b3 = __ballot(v.w != 0);
        if (lane < 4) {
            unsigned long long bv = (lane == 0) ? b0 : (lane == 1) ? b1
                                  : (lane == 2) ? b2 : b3;
            mask_s[j * 4 + lane] = bv;
        }
    }

    // ---- Phase A: h row i = x_i @ W (fp32), a_s/a_d, write hT f16 transposed ----
    float acc[OO];
    #pragma unroll
    for (int o = 0; o < OO; ++o) acc[o] = 0.f;

    const float4* xv = reinterpret_cast<const float4*>(xg + tid * FF);
    const float4* Wv = reinterpret_cast<const float4*>(W);
    for (int k4 = 0; k4 < FF / 4; ++k4) {
        float4 xq = xv[k4];
        float xs[4] = {xq.x, xq.y, xq.z, xq.w};
        #pragma unroll
        for (int kk = 0; kk < 4; ++kk) {
            float xk = xs[kk];
            const float4* wrow = Wv + (k4 * 4 + kk) * (OO / 4);
            #pragma unroll
            for (int o4 = 0; o4 < OO / 4; ++o4) {
                float4 w = wrow[o4];   // wave-uniform -> scalar/broadcast
                acc[o4 * 4 + 0] = fmaf(xk, w.x, acc[o4 * 4 + 0]);
                acc[o4 * 4 + 1] = fmaf(xk, w.y, acc[o4 * 4 + 1]);
                acc[o4 * 4 + 2] = fmaf(xk, w.z, acc[o4 * 4 + 2]);
                acc[o4 * 4 + 3] = fmaf(xk, w.w, acc[o4 * 4 + 3]);
            }
        }
    }

    float as_i = 0.f, ad_i = 0.f;
    {
        const float4* sv = reinterpret_cast<const float4*>(att_src);
        const float4* dv = reinterpret_cast<const float4*>(att_dst);
        #pragma unroll
        for (int o4 = 0; o4 < OO / 4; ++o4) {
            float4 a = sv[o4], d = dv[o4];
            as_i += acc[o4*4+0]*a.x + acc[o4*4+1]*a.y + acc[o4*4+2]*a.z + acc[o4*4+3]*a.w;
            ad_i += acc[o4*4+0]*d.x + acc[o4*4+1]*d.y + acc[o4*4+2]*d.z + acc[o4*4+3]*d.w;
        }
    }
    as_s[tid] = as_i;
    // hT[o][i] = (f16) h[i][o]; lanes write contiguous 2B -> conflict-free
    #pragma unroll
    for (int o = 0; o < OO; ++o) {
        hT[o * HT_STRIDE + tid] = (_Float16)acc[o];
    }
    __syncthreads();

    // ---- Pass 1: m_i and l_i (fp32), cache validity bits in registers ----
    const int wsel = tid & 3;
    const int bsh  = tid >> 2;
    unsigned int mbits[8];
    #pragma unroll
    for (int q = 0; q < 8; ++q) mbits[q] = 0;
    // self-loop always valid
    mbits[tid >> 5] |= (1u << (tid & 31));
    float smax = as_i;   // as_s[tid], self-loop
    #pragma unroll 8
    for (int j = 0; j < NN; ++j) {
        bool nb = (mask_s[j * 4 + wsel] >> bsh) & 1ull;
        if (nb) {
            mbits[j >> 5] |= (1u << (j & 31));
            smax = fmaxf(smax, as_s[j]);
        }
    }
    // leaky_relu monotone increasing -> max(leaky(ad+as_j)) = leaky(ad+max as_j)
    float m = ad_i + smax;
    m = fmaxf(m, 0.2f * m);

    float l = 0.f;
    #pragma unroll 8
    for (int j = 0; j < NN; ++j) {
        float ev = ad_i + as_s[j];
        ev = fmaxf(ev, 0.2f * ev);
        float vmask = ((mbits[j >> 5] >> (j & 31)) & 1u) ? 1.f : 0.f;
        l += vmask * __expf(ev - m);
    }
    float invl = 1.0f / l;   // l >= 1 (diagonal term)

    __syncthreads();   // all mask_s reads done before alpha overwrites region

    // ---- Pass 2: out = alpha @ h via MFMA, 4 j-tiles of 64 ----
    const int r = lane & 15;     // fragment row/col lane index
    const int g = lane >> 4;     // k-chunk selector
    f32x4 dacc[4][4];            // [c (16-row chunk)][nc (16-col chunk)]
    #pragma unroll
    for (int c = 0; c < 4; ++c)
        #pragma unroll
        for (int nc = 0; nc < 4; ++nc)
            dacc[c][nc] = (f32x4){0.f, 0.f, 0.f, 0.f};

    for (int tile = 0; tile < 4; ++tile) {
        // C1: thread i computes alpha[i][tile*64 .. +63] normalized, f16
        #pragma unroll
        for (int c8 = 0; c8 < 8; ++c8) {
            half8 v;
            #pragma unroll
            for (int e8 = 0; e8 < 8; ++e8) {
                int j = tile * 64 + c8 * 8 + e8;
                float ev = ad_i + as_s[j];
                ev = fmaxf(ev, 0.2f * ev);
                float vmask = ((mbits[j >> 5] >> (j & 31)) & 1u) ? 1.f : 0.f;
                float p = vmask * __expf(ev - m) * invl;
                v[e8] = (_Float16)p;
            }
            *(half8*)&al[tid * AL_STRIDE + c8 * 8] = v;
        }
        __syncthreads();

        // C2: wave wv computes rows 64*wv..64*wv+63
        #pragma unroll
        for (int s = 0; s < 2; ++s) {
            half8 af[4], bf[4];
            #pragma unroll
            for (int c = 0; c < 4; ++c)
                af[c] = *(const half8*)&al[(wv * 64 + c * 16 + r) * AL_STRIDE + s * 32 + g * 8];
            #pragma unroll
            for (int nc = 0; nc < 4; ++nc)
                bf[nc] = *(const half8*)&hT[(nc * 16 + r) * HT_STRIDE + tile * 64 + s * 32 + g * 8];
            #pragma unroll
            for (int c = 0; c < 4; ++c)
                #pragma unroll
                for (int nc = 0; nc < 4; ++nc)
                    dacc[c][nc] = __builtin_amdgcn_mfma_f32_16x16x32_f16(
                        af[c], bf[nc], dacc[c][nc], 0, 0, 0);
        }
        __syncthreads();
    }

    // ---- Epilogue: bias + store. D layout: col = lane&15, row = 4*(lane>>4)+q ----
    float bl[4];
    #pragma unroll
    for (int nc = 0; nc < 4; ++nc) bl[nc] = bias[nc * 16 + r];

    #pragma unroll
    for (int c = 0; c < 4; ++c) {
        #pragma unroll
        for (int q = 0; q < 4; ++q) {
            int i_row = wv * 64 + c * 16 + g * 4 + q;
            float* orow = outg + (size_t)i_row * OO;
            #pragma unroll
            for (int nc = 0; nc < 4; ++nc) {
                orow[nc * 16 + r] = dacc[c][nc][q] + bl[nc];
            }
        }
    }
}

extern "C" void kernel_launch(void* const* d_in, const int* in_sizes, int n_in,
                              void* d_out, int out_size, void* d_ws, size_t ws_size,
                              hipStream_t stream) {
    const float* x        = (const float*)d_in[0];
    const int*   adj      = (const int*)  d_in[1];
    const float* W        = (const float*)d_in[2];
    const float* att_src  = (const float*)d_in[3];
    const float* att_dst  = (const float*)d_in[4];
    const float* bias     = (const float*)d_in[5];
    float*       out      = (float*)d_out;

    dim3 grid(1024);
    dim3 block(256);
    hipLaunchKernelGGL(gat_fused, grid, block, 0, stream,
                       x, adj, W, att_src, att_dst, bias, out);
}

// Round 3
// 163.388 us; speedup vs baseline: 2.1216x; 1.6187x over previous
//
#include <hip/hip_runtime.h>
#include <math.h>

// GAT: 1024 independent graphs (B*S), N=256 nodes, F=O=64, H=1.
// One block (256 threads = 4 waves) per graph.
// Phase A: h = x@W fp32 per-thread; scores a_s/a_d fp32; hT f16 to LDS.
// Softmax: m from BLOCK-WIDE max of a_s (upper bound, shift-invariant),
//          single fully-unrolled exp pass -> p (unnormalized) in 128 VGPRs.
// Pass 2:  out = p @ h via v_mfma_f32_16x16x32_f16; normalize by 1/l + bias
//          in the epilogue.

constexpr int NN = 256;
constexpr int FF = 64;
constexpr int OO = 64;
constexpr int HT_STRIDE = 280;  // f16 elems; 560 B rows (odd multiple of 16B)
constexpr int AL_STRIDE = 72;   // f16 elems; 144 B rows (odd multiple of 16B)

constexpr int SMEM_HT  = 64 * HT_STRIDE * 2;    // 35840 B: hT[64][280]
constexpr int SMEM_AL  = NN * AL_STRIDE * 2;    // 36864 B: alpha tile (overlay mask)
constexpr int OFF_AS   = SMEM_HT + SMEM_AL;     // 72704: a_s[256] f32
constexpr int OFF_INVL = OFF_AS + NN * 4;       // 73728: invl[256] f32
constexpr int OFF_RED  = OFF_INVL + NN * 4;     // 74752: red[4] f32
constexpr int SMEM_TOTAL = OFF_RED + 16;        // 74768 B -> 2 blocks/CU

typedef _Float16 half8 __attribute__((ext_vector_type(8)));
typedef float f32x4 __attribute__((ext_vector_type(4)));

__global__ __launch_bounds__(256, 2) void gat_fused(
    const float* __restrict__ x,        // [BS, N, F]
    const int*   __restrict__ adj,      // [BS, N, N]  adj[j][i]!=0 => edge j->i
    const float* __restrict__ W,        // [F, O]
    const float* __restrict__ att_src,  // [O]
    const float* __restrict__ att_dst,  // [O]
    const float* __restrict__ bias,     // [O]
    float* __restrict__ out)            // [BS, N, O]
{
    __shared__ __align__(16) unsigned char smem[SMEM_TOTAL];
    _Float16* hT = (_Float16*)smem;                                     // [64][HT_STRIDE]
    _Float16* al = (_Float16*)(smem + SMEM_HT);                         // [256][AL_STRIDE]
    unsigned long long* mask_s = (unsigned long long*)(smem + SMEM_HT); // overlay on al
    float* as_s   = (float*)(smem + OFF_AS);
    float* invl_s = (float*)(smem + OFF_INVL);
    float* red_s  = (float*)(smem + OFF_RED);

    const int tid  = threadIdx.x;       // target node i
    const int bs   = blockIdx.x;
    const int lane = tid & 63;
    const int wv   = tid >> 6;

    const float* xg   = x + (size_t)bs * NN * FF;
    const int4*  adjv = reinterpret_cast<const int4*>(adj + (size_t)bs * NN * NN);
    float*       outg = out + (size_t)bs * NN * OO;

    // ---- Stage adjacency as bitmap: mask_s[j*4+q] bit ln == (adj[j][4*ln+q]!=0) ----
    #pragma unroll 4
    for (int r4 = 0; r4 < 64; ++r4) {
        int j = r4 * 4 + wv;
        int4 v = adjv[j * 64 + lane];
        unsigned long long b0 = __ballot(v.x != 0);
        unsigned long long b1 = __ballot(v.y != 0);
        unsigned long long b2 = __ballot(v.z != 0);
        unsigned long long b3 = __ballot(v.w != 0);
        if (lane < 4) {
            unsigned long long bv = (lane == 0) ? b0 : (lane == 1) ? b1
                                  : (lane == 2) ? b2 : b3;
            mask_s[j * 4 + lane] = bv;
        }
    }

    // ---- Phase A: h row i = x_i @ W (fp32), scores, hT f16 transposed ----
    float acc[OO];
    #pragma unroll
    for (int o = 0; o < OO; ++o) acc[o] = 0.f;

    const float4* xv = reinterpret_cast<const float4*>(xg + tid * FF);
    const float4* Wv = reinterpret_cast<const float4*>(W);
    for (int k4 = 0; k4 < FF / 4; ++k4) {
        float4 xq = xv[k4];
        float xs[4] = {xq.x, xq.y, xq.z, xq.w};
        #pragma unroll
        for (int kk = 0; kk < 4; ++kk) {
            float xk = xs[kk];
            const float4* wrow = Wv + (k4 * 4 + kk) * (OO / 4);
            #pragma unroll
            for (int o4 = 0; o4 < OO / 4; ++o4) {
                float4 w = wrow[o4];   // wave-uniform
                acc[o4 * 4 + 0] = fmaf(xk, w.x, acc[o4 * 4 + 0]);
                acc[o4 * 4 + 1] = fmaf(xk, w.y, acc[o4 * 4 + 1]);
                acc[o4 * 4 + 2] = fmaf(xk, w.z, acc[o4 * 4 + 2]);
                acc[o4 * 4 + 3] = fmaf(xk, w.w, acc[o4 * 4 + 3]);
            }
        }
    }

    float as_i = 0.f, ad_i = 0.f;
    {
        const float4* sv = reinterpret_cast<const float4*>(att_src);
        const float4* dv = reinterpret_cast<const float4*>(att_dst);
        #pragma unroll
        for (int o4 = 0; o4 < OO / 4; ++o4) {
            float4 a = sv[o4], d = dv[o4];
            as_i += acc[o4*4+0]*a.x + acc[o4*4+1]*a.y + acc[o4*4+2]*a.z + acc[o4*4+3]*a.w;
            ad_i += acc[o4*4+0]*d.x + acc[o4*4+1]*d.y + acc[o4*4+2]*d.z + acc[o4*4+3]*d.w;
        }
    }
    as_s[tid] = as_i;
    #pragma unroll
    for (int o = 0; o < OO; ++o) {
        hT[o * HT_STRIDE + tid] = (_Float16)acc[o];   // contiguous 2B/lane
    }

    // Block-wide max of a_s (upper bound for softmax shift)
    float vmax = as_i;
    #pragma unroll
    for (int off = 32; off > 0; off >>= 1)
        vmax = fmaxf(vmax, __shfl_xor(vmax, off));
    if (lane == 0) red_s[wv] = vmax;
    __syncthreads();   // covers hT, as_s, red_s, mask_s

    const float smax = fmaxf(fmaxf(red_s[0], red_s[1]), fmaxf(red_s[2], red_s[3]));
    float m = ad_i + smax;
    m = fmaxf(m, 0.2f * m);   // = max over ALL j of leaky(ad_i + as_j)

    // ---- Single exp pass: p (unnormalized) -> 32 half8 registers; l in f32 ----
    const int wsel = tid & 3;
    const int bsh  = tid >> 2;
    half8 p_regs[32];
    float lacc[4] = {0.f, 0.f, 0.f, 0.f};

    #pragma unroll
    for (int q8 = 0; q8 < 32; ++q8) {
        float4 aA = *(const float4*)&as_s[q8 * 8];
        float4 aB = *(const float4*)&as_s[q8 * 8 + 4];
        half8 v;
        #define PSTEP(E, AJ) do {                                          \
            const int j = q8 * 8 + (E);                                    \
            unsigned long long w = mask_s[j * 4 + wsel];                   \
            bool valid = (((w >> bsh) & 1ull) != 0) || (j == tid);         \
            float t = ad_i + (AJ);                                         \
            float ev = fmaxf(t, 0.2f * t);                                 \
            float pf = __expf(ev - m);                                     \
            pf = valid ? pf : 0.f;                                         \
            lacc[(E) & 3] += pf;                                           \
            v[E] = (_Float16)pf;                                           \
        } while (0)
        PSTEP(0, aA.x); PSTEP(1, aA.y); PSTEP(2, aA.z); PSTEP(3, aA.w);
        PSTEP(4, aB.x); PSTEP(5, aB.y); PSTEP(6, aB.z); PSTEP(7, aB.w);
        #undef PSTEP
        p_regs[q8] = v;
    }
    const float l = (lacc[0] + lacc[1]) + (lacc[2] + lacc[3]);
    const float invl = 1.0f / l;   // self-loop term > 0 -> l > 0

    __syncthreads();   // all mask_s/as_s reads done before al overwrites region
    invl_s[tid] = invl;

    // ---- Pass 2: out_unnorm = p @ h via MFMA, 4 j-tiles of 64 ----
    const int r = lane & 15;
    const int g = lane >> 4;
    f32x4 dacc[4][4];
    #pragma unroll
    for (int c = 0; c < 4; ++c)
        #pragma unroll
        for (int nc = 0; nc < 4; ++nc)
            dacc[c][nc] = (f32x4){0.f, 0.f, 0.f, 0.f};

    #pragma unroll
    for (int t = 0; t < 4; ++t) {
        #pragma unroll
        for (int c8 = 0; c8 < 8; ++c8)
            *(half8*)&al[tid * AL_STRIDE + c8 * 8] = p_regs[t * 8 + c8];
        __syncthreads();

        #pragma unroll
        for (int s = 0; s < 2; ++s) {
            half8 af[4], bf[4];
            #pragma unroll
            for (int c = 0; c < 4; ++c)
                af[c] = *(const half8*)&al[(wv * 64 + c * 16 + r) * AL_STRIDE + s * 32 + g * 8];
            #pragma unroll
            for (int nc = 0; nc < 4; ++nc)
                bf[nc] = *(const half8*)&hT[(nc * 16 + r) * HT_STRIDE + t * 64 + s * 32 + g * 8];
            #pragma unroll
            for (int c = 0; c < 4; ++c)
                #pragma unroll
                for (int nc = 0; nc < 4; ++nc)
                    dacc[c][nc] = __builtin_amdgcn_mfma_f32_16x16x32_f16(
                        af[c], bf[nc], dacc[c][nc], 0, 0, 0);
        }
        __syncthreads();
    }

    // ---- Epilogue: normalize by invl (per row), + bias, store ----
    float bl[4];
    #pragma unroll
    for (int nc = 0; nc < 4; ++nc) bl[nc] = bias[nc * 16 + r];

    #pragma unroll
    for (int c = 0; c < 4; ++c) {
        #pragma unroll
        for (int q = 0; q < 4; ++q) {
            int i_row = wv * 64 + c * 16 + g * 4 + q;
            float ir = invl_s[i_row];
            float* orow = outg + (size_t)i_row * OO;
            #pragma unroll
            for (int nc = 0; nc < 4; ++nc) {
                orow[nc * 16 + r] = fmaf(dacc[c][nc][q], ir, bl[nc]);
            }
        }
    }
}

extern "C" void kernel_launch(void* const* d_in, const int* in_sizes, int n_in,
                              void* d_out, int out_size, void* d_ws, size_t ws_size,
                              hipStream_t stream) {
    const float* x        = (const float*)d_in[0];
    const int*   adj      = (const int*)  d_in[1];
    const float* W        = (const float*)d_in[2];
    const float* att_src  = (const float*)d_in[3];
    const float* att_dst  = (const float*)d_in[4];
    const float* bias     = (const float*)d_in[5];
    float*       out      = (float*)d_out;

    dim3 grid(1024);
    dim3 block(256);
    hipLaunchKernelGGL(gat_fused, grid, block, 0, stream,
                       x, adj, W, att_src, att_dst, bias, out);
}

// Round 4
// 130.855 us; speedup vs baseline: 2.6491x; 1.2486x over previous
//
#include <hip/hip_runtime.h>
#include <math.h>

// GAT: 1024 graphs (B*S), N=256, F=O=64, H=1. One block (4 waves) per graph.
// Round-4 structure: 53.3KB LDS -> 3 blocks/CU, ONE barrier, wave-local pass 2,
// K=16 MFMA tiles, XOR-swizzled hT, 8-deep adj prefetch.

constexpr int NN = 256;
constexpr int FF = 64;
constexpr int OO = 64;

// LDS layout (bytes)
constexpr int OFF_HT   = 0;        // hT[64][256] f16, XOR-swizzled rows (32768 B)
constexpr int OFF_AL   = 32768;    // al[256][20] f16 (10240 B), rows 40B
constexpr int OFF_MASK = 43008;    // mask u64[256*4] (8192 B)
constexpr int OFF_AS   = 51200;    // a_s f32[256]
constexpr int OFF_INVL = 52224;    // invl f32[256]
constexpr int OFF_RED  = 53248;    // red f32[4]
constexpr int SMEM_TOTAL = 53264;  // <= 54613 -> 3 blocks/CU

typedef _Float16 half4 __attribute__((ext_vector_type(4)));
typedef float f32x4 __attribute__((ext_vector_type(4)));

__global__ __launch_bounds__(256, 3) void gat_fused(
    const float* __restrict__ x,        // [BS, N, F]
    const int*   __restrict__ adj,      // [BS, N, N]  adj[j][i]!=0 => edge j->i
    const float* __restrict__ W,        // [F, O]
    const float* __restrict__ att_src,  // [O]
    const float* __restrict__ att_dst,  // [O]
    const float* __restrict__ bias,     // [O]
    float* __restrict__ out)            // [BS, N, O]
{
    __shared__ __align__(16) unsigned char smem[SMEM_TOTAL];
    _Float16* hT            = (_Float16*)(smem + OFF_HT);
    _Float16* al            = (_Float16*)(smem + OFF_AL);
    unsigned long long* m64 = (unsigned long long*)(smem + OFF_MASK);
    const unsigned* m32     = (const unsigned*)(smem + OFF_MASK);
    float* as_s             = (float*)(smem + OFF_AS);
    float* invl_s           = (float*)(smem + OFF_INVL);
    float* red_s            = (float*)(smem + OFF_RED);

    const int tid  = threadIdx.x;       // target node i
    const int bs   = blockIdx.x;
    const int lane = tid & 63;
    const int wv   = tid >> 6;

    const float* xg   = x + (size_t)bs * NN * FF;
    const int4*  adjv = reinterpret_cast<const int4*>(adj + (size_t)bs * NN * NN);
    float*       outg = out + (size_t)bs * NN * OO;

    // ---- Stage adjacency: wave wv handles rows j = wv*64 .. wv*64+63.
    // mask bit for (row j, col i): m64[j*4 + (i&3)], bit (i>>2).
    // Self-loop (i==j) OR'd in at ballot time: q=j&3 (=k&3 static), pos=j>>2.
    #pragma unroll
    for (int cc = 0; cc < 8; ++cc) {
        int4 v[8];
        #pragma unroll
        for (int k = 0; k < 8; ++k)
            v[k] = adjv[(wv * 64 + cc * 8 + k) * 64 + lane];   // 8 loads in flight
        #pragma unroll
        for (int k = 0; k < 8; ++k) {
            const int j = wv * 64 + cc * 8 + k;
            unsigned long long bb[4];
            bb[0] = __ballot(v[k].x != 0);
            bb[1] = __ballot(v[k].y != 0);
            bb[2] = __ballot(v[k].z != 0);
            bb[3] = __ballot(v[k].w != 0);
            bb[k & 3] |= 1ull << (wv * 16 + cc * 2 + (k >> 2));  // self-loop
            if (lane < 4) {
                unsigned long long bv = (lane == 0) ? bb[0] : (lane == 1) ? bb[1]
                                      : (lane == 2) ? bb[2] : bb[3];
                m64[j * 4 + lane] = bv;
            }
        }
    }

    // ---- Phase A: h row i = x_i @ W (fp32); scores; hT f16 swizzled ----
    float acc[OO];
    #pragma unroll
    for (int o = 0; o < OO; ++o) acc[o] = 0.f;

    const float4* xv = reinterpret_cast<const float4*>(xg + tid * FF);
    const float4* Wv = reinterpret_cast<const float4*>(W);
    for (int k4 = 0; k4 < FF / 4; ++k4) {
        float4 xq = xv[k4];
        float xs[4] = {xq.x, xq.y, xq.z, xq.w};
        #pragma unroll
        for (int kk = 0; kk < 4; ++kk) {
            float xk = xs[kk];
            const float4* wrow = Wv + (k4 * 4 + kk) * (OO / 4);
            #pragma unroll
            for (int o4 = 0; o4 < OO / 4; ++o4) {
                float4 w = wrow[o4];   // wave-uniform -> scalar loads
                acc[o4 * 4 + 0] = fmaf(xk, w.x, acc[o4 * 4 + 0]);
                acc[o4 * 4 + 1] = fmaf(xk, w.y, acc[o4 * 4 + 1]);
                acc[o4 * 4 + 2] = fmaf(xk, w.z, acc[o4 * 4 + 2]);
                acc[o4 * 4 + 3] = fmaf(xk, w.w, acc[o4 * 4 + 3]);
            }
        }
    }

    float as_i = 0.f, ad_i = 0.f;
    {
        const float4* sv = reinterpret_cast<const float4*>(att_src);
        const float4* dv = reinterpret_cast<const float4*>(att_dst);
        #pragma unroll
        for (int o4 = 0; o4 < OO / 4; ++o4) {
            float4 a = sv[o4], d = dv[o4];
            as_i += acc[o4*4+0]*a.x + acc[o4*4+1]*a.y + acc[o4*4+2]*a.z + acc[o4*4+3]*a.w;
            ad_i += acc[o4*4+0]*d.x + acc[o4*4+1]*d.y + acc[o4*4+2]*d.z + acc[o4*4+3]*d.w;
        }
    }
    as_s[tid] = as_i;
    // hT[o][tid] with byte ^= ((o&7)<<4) swizzle (stays within the 512B row)
    #pragma unroll
    for (int o = 0; o < OO; ++o) {
        int boff = o * 512 + ((2 * tid) ^ ((o & 7) << 4));
        *(_Float16*)(smem + OFF_HT + boff) = (_Float16)acc[o];
    }

    // Block-wide max of a_s (softmax shift upper bound)
    float vmax = as_i;
    #pragma unroll
    for (int off = 32; off > 0; off >>= 1)
        vmax = fmaxf(vmax, __shfl_xor(vmax, off));
    if (lane == 0) red_s[wv] = vmax;

    __syncthreads();   // the ONLY barrier: mask, hT, as_s, red_s all visible

    const float smax = fmaxf(fmaxf(red_s[0], red_s[1]), fmaxf(red_s[2], red_s[3]));
    float mm = ad_i + smax;
    mm = fmaxf(mm, 0.2f * mm);              // >= leaky(ad_i + as_j) for ALL j
    const float adm = ad_i - mm;            // u = adm + as_j
    const float c2  = fmaf(0.2f, ad_i, -mm);// v = fma(0.2, as_j, c2)

    const int woff = ((tid & 3) << 1) + (tid >> 7);  // dword sel within mask row
    const int bitp = (tid >> 2) & 31;
    const int r = lane & 15;
    const int g = lane >> 4;

    // Pass-2 per-lane address bases
    const int albase = tid * 40;                       // al write row (bytes)
    int afbase[4];
    #pragma unroll
    for (int c = 0; c < 4; ++c)
        afbase[c] = (wv * 64 + c * 16 + r) * 40 + g * 8;
    int bfbase[4];
    const int lo = (g * 8) ^ ((r & 1) << 4);           // low-5-bit part of k-offset
    const int xh = ((r >> 1) & 3) * 32;                // high swizzle bits
    #pragma unroll
    for (int nc = 0; nc < 4; ++nc)
        bfbase[nc] = (nc * 16 + r) * 512 + lo;

    f32x4 dacc[4][4];
    #pragma unroll
    for (int c = 0; c < 4; ++c)
        #pragma unroll
        for (int nc = 0; nc < 4; ++nc)
            dacc[c][nc] = (f32x4){0.f, 0.f, 0.f, 0.f};

    float lacc[4] = {0.f, 0.f, 0.f, 0.f};

    // ---- Pass 2: 16 j-tiles of 16, barrier-free (wave-local al) ----
    #pragma unroll
    for (int t = 0; t < 16; ++t) {
        // alpha (unnormalized, f16) for this thread's row, j = t*16 .. +15
        #pragma unroll
        for (int q = 0; q < 4; ++q) {
            half4 hq;
            #pragma unroll
            for (int e = 0; e < 4; ++e) {
                const int j = t * 16 + q * 4 + e;
                unsigned w = m32[j * 8 + woff];              // LDS, imm offset
                float aj = as_s[j];                          // LDS, imm offset
                float u  = adm + aj;
                float vv = fmaf(0.2f, aj, c2);
                float ev = fmaxf(u, vv);                     // leaky - m
                float pf = __expf(ev);
                bool valid = (w >> bitp) & 1u;
                pf = valid ? pf : 0.f;
                lacc[e] += pf;
                hq[e] = (_Float16)pf;
            }
            *(half4*)(smem + OFF_AL + albase + q * 8) = hq;
        }
        asm volatile("" ::: "memory");   // pin al writes before af reads (DS is in-order)

        half4 bf[4];
        const int kx = (t * 32) ^ xh;
        #pragma unroll
        for (int nc = 0; nc < 4; ++nc)
            bf[nc] = *(const half4*)(smem + OFF_HT + bfbase[nc] + kx);
        #pragma unroll
        for (int c = 0; c < 4; ++c) {
            half4 af = *(const half4*)(smem + OFF_AL + afbase[c]);
            #pragma unroll
            for (int nc = 0; nc < 4; ++nc)
                dacc[c][nc] = __builtin_amdgcn_mfma_f32_16x16x16f16(
                    af, bf[nc], dacc[c][nc], 0, 0, 0);
        }
    }

    const float l = (lacc[0] + lacc[1]) + (lacc[2] + lacc[3]);
    invl_s[tid] = 1.0f / l;          // l >= self term > 0
    asm volatile("" ::: "memory");   // invl writes before wave-local reads

    // ---- Epilogue: normalize + bias, direct stores ----
    float bl[4];
    #pragma unroll
    for (int nc = 0; nc < 4; ++nc) bl[nc] = bias[nc * 16 + r];

    #pragma unroll
    for (int c = 0; c < 4; ++c) {
        #pragma unroll
        for (int q = 0; q < 4; ++q) {
            const int i_row = wv * 64 + c * 16 + g * 4 + q;
            float ir = invl_s[i_row];                        // wave-local
            float* orow = outg + (size_t)i_row * OO;
            #pragma unroll
            for (int nc = 0; nc < 4; ++nc)
                orow[nc * 16 + r] = fmaf(dacc[c][nc][q], ir, bl[nc]);
        }
    }
}

extern "C" void kernel_launch(void* const* d_in, const int* in_sizes, int n_in,
                              void* d_out, int out_size, void* d_ws, size_t ws_size,
                              hipStream_t stream) {
    const float* x        = (const float*)d_in[0];
    const int*   adj      = (const int*)  d_in[1];
    const float* W        = (const float*)d_in[2];
    const float* att_src  = (const float*)d_in[3];
    const float* att_dst  = (const float*)d_in[4];
    const float* bias     = (const float*)d_in[5];
    float*       out      = (float*)d_out;

    dim3 grid(1024);
    dim3 block(256);
    hipLaunchKernelGGL(gat_fused, grid, block, 0, stream,
                       x, adj, W, att_src, att_dst, bias, out);
}